// Round 5
// baseline (76.356 us; speedup 1.0000x reference)
//
#include <hip/hip_runtime.h>
#include <hip/hip_bf16.h>

#define NN 8192
#define KK 256
#define HN 4096
#define TS 128   // square tile
#define BK 64
#define NBLK 2080  // lower-tri incl. diagonal: 64*65/2 = 8*260

typedef __attribute__((ext_vector_type(8))) short bf16x8;
typedef __attribute__((ext_vector_type(4))) float f32x4;

__device__ __forceinline__ void gload_lds16(const void* g, void* l) {
  __builtin_amdgcn_global_load_lds(
      (const __attribute__((address_space(1))) unsigned int*)g,
      (__attribute__((address_space(3))) unsigned int*)l, 16, 0, 0);
}

// ---- Kernel 1: row-normalize z (f32) -> zn (bf16); block 0 zeroes out ----
__global__ void nrm_kernel(const float* __restrict__ z,
                           unsigned short* __restrict__ zn,
                           float* __restrict__ out) {
  if (blockIdx.x == 0 && threadIdx.x == 0) out[0] = 0.0f;
  int row = (blockIdx.x << 2) + (threadIdx.x >> 6);
  int lane = threadIdx.x & 63;
  float4 v = ((const float4*)(z + (size_t)row * KK))[lane];
  float ss = v.x * v.x + v.y * v.y + v.z * v.z + v.w * v.w;
#pragma unroll
  for (int off = 32; off; off >>= 1) ss += __shfl_xor(ss, off, 64);
  float scale = 1.0f / fmaxf(sqrtf(ss), 1e-8f);
  union {
    __hip_bfloat16 h[4];
    ushort4 u;
  } cv;
  cv.h[0] = __float2bfloat16(v.x * scale);
  cv.h[1] = __float2bfloat16(v.y * scale);
  cv.h[2] = __float2bfloat16(v.z * scale);
  cv.h[3] = __float2bfloat16(v.w * scale);
  ((ushort4*)zn)[(size_t)row * 64 + lane] = cv.u;
}

// ---- Kernel 2: symmetric Gram-GEMM, 128x128 lower-triangle tiles ----
// p = exp(10*s_ij - 10) for j<i. Block (s,bn) writes per-wave-private
// slots: rowpartT[2bn+wc][row] (float4) and colpartT[2s+wr][col].
// No atomics, no epilogue barriers. pos pairs (i,i^4096) are always in a
// strictly-lower tile (s>=32, bn=s-32): write both directions there.
__global__ __launch_bounds__(256, 3) void gemm_kernel(
    const unsigned short* __restrict__ zn, float* __restrict__ rowpartT,
    float* __restrict__ colpartT, float* __restrict__ pos) {
  __shared__ short As[TS * BK];  // 16 KiB, XOR-swizzled 16B groups
  __shared__ short Bs[TS * BK];  // 16 KiB

  const int t = threadIdx.x;
  // XCD-aware bijective swizzle (2080 = 8*260), then triangular decode
  int id = ((int)blockIdx.x & 7) * 260 + ((int)blockIdx.x >> 3);
  int s = (int)((sqrtf((float)(8 * id + 1)) - 1.0f) * 0.5f);
  while (s * (s + 1) / 2 > id) --s;
  while ((s + 1) * (s + 2) / 2 <= id) ++s;
  const int bn = id - s * (s + 1) / 2;  // 0..s (bn==s is the diagonal tile)

  const int l = t & 63;
  const int w = t >> 6;   // 0..3
  const int wr = w >> 1;  // 0..1 : 64-row half
  const int wc = w & 1;   // 0..1 : 64-col half

  f32x4 acc[4][4];
  const f32x4 vzero = {0.f, 0.f, 0.f, 0.f};
#pragma unroll
  for (int mi = 0; mi < 4; ++mi)
#pragma unroll
    for (int ni = 0; ni < 4; ++ni) acc[mi][ni] = vzero;

  const char* zb = (const char*)zn;
  const int rloc = t >> 3;                // 0..31
  const int gsrc = (t & 7) ^ (rloc & 7);  // pre-swizzled source 16B-group

#pragma unroll
  for (int kt = 0; kt < KK / BK; ++kt) {
    if (kt) __syncthreads();  // previous tile fully consumed
#pragma unroll
    for (int ro = 0; ro < 4; ++ro) {  // A: 128 rows
      int r = ro * 32 + rloc;
      gload_lds16(zb + (size_t)(s * TS + r) * 512 + kt * 128 + gsrc * 16,
                  (char*)As + ro * 4096 + t * 16);
    }
#pragma unroll
    for (int ro = 0; ro < 4; ++ro) {  // B: 128 rows
      int r = ro * 32 + rloc;
      gload_lds16(zb + (size_t)(bn * TS + r) * 512 + kt * 128 + gsrc * 16,
                  (char*)Bs + ro * 4096 + t * 16);
    }
    asm volatile("s_waitcnt vmcnt(0)" ::: "memory");
    __syncthreads();

#pragma unroll
    for (int kk = 0; kk < 2; ++kk) {
      bf16x8 af[4], bfr[4];
      int g = kk * 4 + (l >> 4);
#pragma unroll
      for (int mi = 0; mi < 4; ++mi) {
        int r = wr * 64 + mi * 16 + (l & 15);
        af[mi] = *(const bf16x8*)(As + r * 64 + ((g ^ (r & 7)) << 3));
      }
#pragma unroll
      for (int ni = 0; ni < 4; ++ni) {
        int r = wc * 64 + ni * 16 + (l & 15);
        bfr[ni] = *(const bf16x8*)(Bs + r * 64 + ((g ^ (r & 7)) << 3));
      }
#pragma unroll
      for (int mi = 0; mi < 4; ++mi)
#pragma unroll
        for (int ni = 0; ni < 4; ++ni)
          acc[mi][ni] = __builtin_amdgcn_mfma_f32_16x16x32_bf16(
              af[mi], bfr[ni], acc[mi][ni], 0, 0, 0);
    }
  }

  // ---- epilogue: p = exp(10s-10) for gc<gr only; private partial slots ----
  const int g16 = l >> 4;
  const int rowBase = s * TS + wr * 64 + (g16 << 2);
  const int colBase = bn * TS + wc * 64 + (l & 15);
  const float C1 = 14.4269504088896340736f;  // 10*log2(e)
  float rs[4][4];
  float cs[4] = {0.f, 0.f, 0.f, 0.f};
#pragma unroll
  for (int mi = 0; mi < 4; ++mi) {
#pragma unroll
    for (int j = 0; j < 4; ++j) rs[mi][j] = 0.f;
#pragma unroll
    for (int ni = 0; ni < 4; ++ni) {
#pragma unroll
      for (int j = 0; j < 4; ++j) {
        int gr = rowBase + mi * 16 + j;
        int gc = colBase + ni * 16;
        float a = acc[mi][ni][j];
        if (gc == (gr ^ HN)) {  // strictly-lower hit: write both directions
          pos[gr] = a * 10.0f;
          pos[gc] = a * 10.0f;
        }
        float p = (gc < gr) ? exp2f(fmaf(a, C1, -C1)) : 0.0f;
        rs[mi][j] += p;
        cs[ni] += p;
      }
    }
  }
  // reduce rs across the 16 col-lanes; cs across the 4 row-lane groups
#pragma unroll
  for (int mi = 0; mi < 4; ++mi)
#pragma unroll
    for (int j = 0; j < 4; ++j) {
      float v = rs[mi][j];
      v += __shfl_xor(v, 1, 64);
      v += __shfl_xor(v, 2, 64);
      v += __shfl_xor(v, 4, 64);
      v += __shfl_xor(v, 8, 64);
      rs[mi][j] = v;
    }
#pragma unroll
  for (int ni = 0; ni < 4; ++ni) {
    float v = cs[ni];
    v += __shfl_xor(v, 16, 64);
    v += __shfl_xor(v, 32, 64);
    cs[ni] = v;  // valid in lanes l<16
  }
  // private-slot stores: no cross-wave merge needed
  if ((l & 15) == 0) {
    float* dst = rowpartT + (size_t)(2 * bn + wc) * NN;
#pragma unroll
    for (int mi = 0; mi < 4; ++mi) {
      float4 v4 = make_float4(rs[mi][0], rs[mi][1], rs[mi][2], rs[mi][3]);
      *(float4*)(dst + rowBase + mi * 16) = v4;
    }
  }
  if (l < 16) {
    float* dst = colpartT + (size_t)(2 * s + wr) * NN;
#pragma unroll
    for (int ni = 0; ni < 4; ++ni) dst[colBase + ni * 16] = cs[ni];
  }
}

// ---- Kernel 3: loss = mean(10 + ln(rowsum_i) - pos_i) ----
__global__ void finalize_kernel(const float* __restrict__ rowpartT,
                                const float* __restrict__ colpartT,
                                const float* __restrict__ pos,
                                float* __restrict__ out) {
  int i = blockIdx.x * 256 + threadIdx.x;  // one row per thread
  int si = i >> 7;
  float sum = 0.f;
  // row partials: slots 0 .. 2*si+1 (blocks (si, bn<=si), both wc halves)
  for (int k = 0; k <= 2 * si + 1; ++k) sum += rowpartT[(size_t)k * NN + i];
  // col partials: slots 2*si .. 127 (blocks (s>=si, bn=si), both wr halves)
  for (int k = 2 * si; k < 128; ++k) sum += colpartT[(size_t)k * NN + i];
  float acc = 10.0f + logf(sum) - pos[i];
#pragma unroll
  for (int off = 32; off; off >>= 1) acc += __shfl_xor(acc, off, 64);
  __shared__ float ws[4];
  if ((threadIdx.x & 63) == 0) ws[threadIdx.x >> 6] = acc;
  __syncthreads();
  if (threadIdx.x == 0)
    atomicAdd(out, (ws[0] + ws[1] + ws[2] + ws[3]) * (1.0f / (float)NN));
}

extern "C" void kernel_launch(void* const* d_in, const int* in_sizes, int n_in,
                              void* d_out, int out_size, void* d_ws,
                              size_t ws_size, hipStream_t stream) {
  const float* z = (const float*)d_in[0];
  float* out = (float*)d_out;
  char* ws = (char*)d_ws;
  unsigned short* zn = (unsigned short*)ws;      // 4 MiB bf16
  float* rowpartT = (float*)(ws + (4 << 20));    // 4 MiB [128][8192]
  float* colpartT = (float*)(ws + (8 << 20));    // 4 MiB [128][8192]
  float* pos = (float*)(ws + (12 << 20));        // 32 KiB

  nrm_kernel<<<NN / 4, 256, 0, stream>>>(z, zn, out);
  gemm_kernel<<<NBLK, 256, 0, stream>>>(zn, rowpartT, colpartT, pos);
  finalize_kernel<<<NN / 256, 256, 0, stream>>>(rowpartT, colpartT, pos, out);
}